// Round 1
// baseline (14197.820 us; speedup 1.0000x reference)
//
#include <hip/hip_runtime.h>
#include <hip/hip_bf16.h>
#include <math.h>

// Problem constants
#define B_  4
#define S_  512
#define H_  768
#define NH_ 12
#define DH_ 64
#define FF_ 3072
#define L_  6
#define V_  30522

// ---------------------------------------------------------------------------
// Embedding gather + LayerNorm.  One block per token (B*S blocks, 256 thr).
// x[t,:] = LN(word_emb[ids[t]] + pos_emb[s] + type_emb[tt[t]])
// ---------------------------------------------------------------------------
__global__ __launch_bounds__(256) void embed_ln_kernel(
    const int* __restrict__ ids, const int* __restrict__ tt,
    const float* __restrict__ wemb, const float* __restrict__ pemb,
    const float* __restrict__ temb, const float* __restrict__ g,
    const float* __restrict__ bb, float* __restrict__ x)
{
    const int t = blockIdx.x;            // token index in [0, B*S)
    const int s = t % S_;
    const int tid = threadIdx.x;
    __shared__ float red[256];

    const float* wr = wemb + (size_t)ids[t] * H_;
    const float* pr = pemb + (size_t)s * H_;
    const float* tr = temb + (size_t)tt[t] * H_;

    float v[3];
    float sum = 0.f;
#pragma unroll
    for (int i = 0; i < 3; i++) {
        int c = tid + i * 256;
        v[i] = wr[c] + pr[c] + tr[c];
        sum += v[i];
    }
    red[tid] = sum; __syncthreads();
    for (int st = 128; st > 0; st >>= 1) { if (tid < st) red[tid] += red[tid + st]; __syncthreads(); }
    const float mean = red[0] / (float)H_;
    __syncthreads();
    float s2 = 0.f;
#pragma unroll
    for (int i = 0; i < 3; i++) { float d = v[i] - mean; s2 += d * d; }
    red[tid] = s2; __syncthreads();
    for (int st = 128; st > 0; st >>= 1) { if (tid < st) red[tid] += red[tid + st]; __syncthreads(); }
    const float rstd = rsqrtf(red[0] / (float)H_ + 1e-12f);
#pragma unroll
    for (int i = 0; i < 3; i++) {
        int c = tid + i * 256;
        x[(size_t)t * H_ + c] = (v[i] - mean) * rstd * g[c] + bb[c];
    }
}

// ---------------------------------------------------------------------------
// Tiled fp32 GEMM: C[M,N] = A[M,K] @ W[K,N] + bias[N], optional exact GELU.
// BM=BN=64, BK=16, 256 threads, 4x4 per thread.  All dims are multiples.
// ---------------------------------------------------------------------------
#define BM 64
#define BN 64
#define BK 16

template<int EPI>   // 0 = none, 1 = gelu(exact)
__global__ __launch_bounds__(256) void gemm_bias_kernel(
    const float* __restrict__ A, const float* __restrict__ W,
    const float* __restrict__ bias, float* __restrict__ C,
    int M, int K, int N)
{
    __shared__ float As[BK][BM + 1];
    __shared__ float Bs[BK][BN];
    const int tid = threadIdx.x;
    const int tx = tid & 15;      // 0..15 -> n
    const int ty = tid >> 4;      // 0..15 -> m
    const int m0 = blockIdx.y * BM;
    const int n0 = blockIdx.x * BN;

    float acc[4][4] = {};

    for (int k0 = 0; k0 < K; k0 += BK) {
#pragma unroll
        for (int i = 0; i < 4; i++) {
            int lin = tid + i * 256;
            int r = lin >> 4, c = lin & 15;          // r: m-offset, c: k-offset
            As[c][r] = A[(size_t)(m0 + r) * K + k0 + c];
        }
#pragma unroll
        for (int i = 0; i < 4; i++) {
            int lin = tid + i * 256;
            int r = lin >> 6, c = lin & 63;          // r: k-offset, c: n-offset
            Bs[r][c] = W[(size_t)(k0 + r) * N + n0 + c];
        }
        __syncthreads();
#pragma unroll
        for (int kk = 0; kk < BK; kk++) {
            float a[4], w[4];
#pragma unroll
            for (int i = 0; i < 4; i++) a[i] = As[kk][ty * 4 + i];
#pragma unroll
            for (int j = 0; j < 4; j++) w[j] = Bs[kk][tx * 4 + j];
#pragma unroll
            for (int i = 0; i < 4; i++)
#pragma unroll
                for (int j = 0; j < 4; j++)
                    acc[i][j] += a[i] * w[j];
        }
        __syncthreads();
    }

#pragma unroll
    for (int i = 0; i < 4; i++) {
        int m = m0 + ty * 4 + i;
#pragma unroll
        for (int j = 0; j < 4; j++) {
            int n = n0 + tx * 4 + j;
            float v = acc[i][j] + bias[n];
            if (EPI == 1) v = v * 0.5f * (1.0f + erff(v * 0.70710678118654752f));
            C[(size_t)m * N + n] = v;
        }
    }
}

// ---------------------------------------------------------------------------
// Attention: one block per (q, head, batch).  256 threads = 4 waves.
// Q,K,V layout: [B,S,NH,DH] (i.e. [B,S,H] with head-major inner split).
// ---------------------------------------------------------------------------
__global__ __launch_bounds__(256) void attention_kernel(
    const float* __restrict__ Q, const float* __restrict__ K,
    const float* __restrict__ V, const int* __restrict__ amask,
    float* __restrict__ O)
{
    const int qi = blockIdx.x, h = blockIdx.y, b = blockIdx.z;
    const int tid = threadIdx.x;
    const int lane = tid & 63;
    const int wave = tid >> 6;

    __shared__ float qs[DH_];
    __shared__ float sc[S_];
    __shared__ float red[256];

    const size_t headoff = (size_t)h * DH_;
    if (tid < DH_) qs[tid] = Q[((size_t)(b * S_ + qi) * H_) + headoff + tid];
    __syncthreads();

    // scores: each wave handles every 4th key; lanes over DH, shuffle-reduce
    for (int k = wave; k < S_; k += 4) {
        const float* kp = K + ((size_t)(b * S_ + k) * H_) + headoff;
        float p = qs[lane] * kp[lane];
#pragma unroll
        for (int off = 32; off > 0; off >>= 1) p += __shfl_down(p, off);
        if (lane == 0)
            sc[k] = p * 0.125f + (amask[b * S_ + k] ? 0.f : -1e9f);
    }
    __syncthreads();

    // softmax over sc[0..511]
    float m = -INFINITY;
    for (int k = tid; k < S_; k += 256) m = fmaxf(m, sc[k]);
    red[tid] = m; __syncthreads();
    for (int st = 128; st > 0; st >>= 1) { if (tid < st) red[tid] = fmaxf(red[tid], red[tid + st]); __syncthreads(); }
    m = red[0]; __syncthreads();

    float sum = 0.f;
    for (int k = tid; k < S_; k += 256) { float e = __expf(sc[k] - m); sc[k] = e; sum += e; }
    red[tid] = sum; __syncthreads();
    for (int st = 128; st > 0; st >>= 1) { if (tid < st) red[tid] += red[tid + st]; __syncthreads(); }
    const float inv = 1.0f / red[0];
    __syncthreads();

    // PV: wave w accumulates keys w, w+4, ...; lane = d (coalesced V reads)
    float acc = 0.f;
    for (int k = wave; k < S_; k += 4)
        acc += sc[k] * V[((size_t)(b * S_ + k) * H_) + headoff + lane];
    red[tid] = acc; __syncthreads();
    if (tid < DH_) {
        float o = (red[tid] + red[tid + 64] + red[tid + 128] + red[tid + 192]) * inv;
        O[((size_t)(b * S_ + qi) * H_) + headoff + tid] = o;
    }
}

// ---------------------------------------------------------------------------
// x = LN(x + delta), per-token block, in place.
// ---------------------------------------------------------------------------
__global__ __launch_bounds__(256) void add_ln_kernel(
    float* __restrict__ x, const float* __restrict__ delta,
    const float* __restrict__ g, const float* __restrict__ bb)
{
    const int t = blockIdx.x;
    const int tid = threadIdx.x;
    __shared__ float red[256];
    const size_t base = (size_t)t * H_;

    float v[3];
    float sum = 0.f;
#pragma unroll
    for (int i = 0; i < 3; i++) {
        int c = tid + i * 256;
        v[i] = x[base + c] + delta[base + c];
        sum += v[i];
    }
    red[tid] = sum; __syncthreads();
    for (int st = 128; st > 0; st >>= 1) { if (tid < st) red[tid] += red[tid + st]; __syncthreads(); }
    const float mean = red[0] / (float)H_;
    __syncthreads();
    float s2 = 0.f;
#pragma unroll
    for (int i = 0; i < 3; i++) { float d = v[i] - mean; s2 += d * d; }
    red[tid] = s2; __syncthreads();
    for (int st = 128; st > 0; st >>= 1) { if (tid < st) red[tid] += red[tid + st]; __syncthreads(); }
    const float rstd = rsqrtf(red[0] / (float)H_ + 1e-12f);
#pragma unroll
    for (int i = 0; i < 3; i++) {
        int c = tid + i * 256;
        x[base + c] = (v[i] - mean) * rstd * g[c] + bb[c];
    }
}

// ---------------------------------------------------------------------------
// QA head: emissions[t, 0..1] = x[t,:] @ qa_w + qa_b.  One block per token.
// ---------------------------------------------------------------------------
__global__ __launch_bounds__(256) void qa_kernel(
    const float* __restrict__ x, const float* __restrict__ qa_w,
    const float* __restrict__ qa_b, float* __restrict__ em)
{
    const int t = blockIdx.x;
    const int tid = threadIdx.x;
    __shared__ float r0[256], r1[256];
    float s0 = 0.f, s1 = 0.f;
#pragma unroll
    for (int i = 0; i < 3; i++) {
        int c = tid + i * 256;
        float xv = x[(size_t)t * H_ + c];
        s0 += xv * qa_w[c * 2 + 0];
        s1 += xv * qa_w[c * 2 + 1];
    }
    r0[tid] = s0; r1[tid] = s1; __syncthreads();
    for (int st = 128; st > 0; st >>= 1) {
        if (tid < st) { r0[tid] += r0[tid + st]; r1[tid] += r1[tid + st]; }
        __syncthreads();
    }
    if (tid == 0) {
        em[(size_t)t * 2 + 0] = r0[0] + qa_b[0];
        em[(size_t)t * 2 + 1] = r1[0] + qa_b[1];
    }
}

// ---------------------------------------------------------------------------
// CRF: one block; lane b < 4 handles one sequence serially (2 tags, S=512).
// ---------------------------------------------------------------------------
__device__ __forceinline__ float lse2(float a, float b) {
    float m = fmaxf(a, b);
    return m + log1pf(expf(-fabsf(a - b)));
}

__global__ void crf_kernel(
    const float* __restrict__ em, const int* __restrict__ amask,
    const int* __restrict__ spos, const int* __restrict__ epos,
    const float* __restrict__ startT, const float* __restrict__ endT,
    const float* __restrict__ trans, float* __restrict__ out)
{
    __shared__ float partial[B_];
    const int b = threadIdx.x;
    if (b < B_) {
        const int sp = spos[b], ep = epos[b];
        const bool valid = (sp >= 0) && (sp < S_) && (ep >= 0) && (ep < S_) && (sp <= ep);
        const float* e = em + (size_t)b * S_ * 2;
        const int* mk = amask + b * S_;
        const float t00 = trans[0], t01 = trans[1], t10 = trans[2], t11 = trans[3];

        int prev = (valid && 0 >= sp && 0 <= ep) ? 1 : 0;
        float num = startT[prev] + e[prev];
        float a0 = startT[0] + e[0];
        float a1 = startT[1] + e[1];
        int msum = mk[0] ? 1 : 0;

        for (int t = 1; t < S_; t++) {
            const int cur = (valid && t >= sp && t <= ep) ? 1 : 0;
            const float e0 = e[t * 2 + 0], e1 = e[t * 2 + 1];
            const float mf = mk[t] ? 1.f : 0.f;
            const float tr = prev ? (cur ? t11 : t10) : (cur ? t01 : t00);
            num += (tr + (cur ? e1 : e0)) * mf;
            const float n0 = lse2(a0 + t00, a1 + t10) + e0;
            const float n1 = lse2(a0 + t01, a1 + t11) + e1;
            if (mk[t]) { a0 = n0; a1 = n1; }
            msum += mk[t] ? 1 : 0;
            prev = cur;
        }
        const int last_idx = msum - 1;
        const int last_lab = (valid && last_idx >= sp && last_idx <= ep) ? 1 : 0;
        num += endT[last_lab];
        const float logZ = lse2(a0 + endT[0], a1 + endT[1]);
        partial[b] = num - logZ;
    }
    __syncthreads();
    if (threadIdx.x == 0)
        out[0] = -(partial[0] + partial[1] + partial[2] + partial[3]);
}

// ---------------------------------------------------------------------------
// Launch
// ---------------------------------------------------------------------------
extern "C" void kernel_launch(void* const* d_in, const int* in_sizes, int n_in,
                              void* d_out, int out_size, void* d_ws, size_t ws_size,
                              hipStream_t stream)
{
    const int*   input_ids  = (const int*)  d_in[0];
    const int*   attn_mask  = (const int*)  d_in[1];
    const int*   token_type = (const int*)  d_in[2];
    const int*   start_pos  = (const int*)  d_in[3];
    const int*   end_pos    = (const int*)  d_in[4];
    const float* word_emb   = (const float*)d_in[5];
    const float* pos_emb    = (const float*)d_in[6];
    const float* type_emb   = (const float*)d_in[7];
    const float* emb_ln_g   = (const float*)d_in[8];
    const float* emb_ln_b   = (const float*)d_in[9];
    const float* Wq         = (const float*)d_in[10];
    const float* bq         = (const float*)d_in[11];
    const float* Wk         = (const float*)d_in[12];
    const float* bk         = (const float*)d_in[13];
    const float* Wv         = (const float*)d_in[14];
    const float* bv         = (const float*)d_in[15];
    const float* Wo         = (const float*)d_in[16];
    const float* bo         = (const float*)d_in[17];
    const float* ln1_g      = (const float*)d_in[18];
    const float* ln1_b      = (const float*)d_in[19];
    const float* W1         = (const float*)d_in[20];
    const float* b1         = (const float*)d_in[21];
    const float* W2         = (const float*)d_in[22];
    const float* b2         = (const float*)d_in[23];
    const float* ln2_g      = (const float*)d_in[24];
    const float* ln2_b      = (const float*)d_in[25];
    const float* qa_w       = (const float*)d_in[26];
    const float* qa_b       = (const float*)d_in[27];
    const float* crf_start  = (const float*)d_in[28];
    const float* crf_end    = (const float*)d_in[29];
    const float* crf_trans  = (const float*)d_in[30];
    float* out = (float*)d_out;

    const int M = B_ * S_;                 // 2048 tokens
    // Workspace carve-up (floats):
    //   x        : M*H              (persistent activations)
    //   scratch  : M*FF             (used as q|k|v|ctx quadrants OR as ffn-h)
    //   tmp768   : M*H              (proj outputs before residual+LN)
    //   emis     : M*2
    float* ws  = (float*)d_ws;
    float* x      = ws;
    float* scr    = x + (size_t)M * H_;            // M*FF floats
    float* tmp768 = scr + (size_t)M * FF_;
    float* emis   = tmp768 + (size_t)M * H_;
    float* qb  = scr;
    float* kb  = qb + (size_t)M * H_;
    float* vb  = kb + (size_t)M * H_;
    float* ctx = vb + (size_t)M * H_;
    float* hb  = scr;                               // aliases q/k/v/ctx (disjoint in time)

    dim3 blk(256);

    // Embeddings + LN
    embed_ln_kernel<<<M, blk, 0, stream>>>(input_ids, token_type, word_emb, pos_emb,
                                           type_emb, emb_ln_g, emb_ln_b, x);

    const dim3 gH(H_ / BN, M / BM);    // GEMM grid for N=768
    const dim3 gF(FF_ / BN, M / BM);   // GEMM grid for N=3072
    const dim3 gA(S_, NH_, B_);        // attention grid

    for (int l = 0; l < L_; l++) {
        const float* wq = Wq + (size_t)l * H_ * H_;
        const float* wk = Wk + (size_t)l * H_ * H_;
        const float* wv = Wv + (size_t)l * H_ * H_;
        const float* wo = Wo + (size_t)l * H_ * H_;
        const float* w1 = W1 + (size_t)l * H_ * FF_;
        const float* w2 = W2 + (size_t)l * FF_ * H_;

        gemm_bias_kernel<0><<<gH, blk, 0, stream>>>(x, wq, bq + l * H_, qb, M, H_, H_);
        gemm_bias_kernel<0><<<gH, blk, 0, stream>>>(x, wk, bk + l * H_, kb, M, H_, H_);
        gemm_bias_kernel<0><<<gH, blk, 0, stream>>>(x, wv, bv + l * H_, vb, M, H_, H_);

        attention_kernel<<<gA, blk, 0, stream>>>(qb, kb, vb, attn_mask, ctx);

        gemm_bias_kernel<0><<<gH, blk, 0, stream>>>(ctx, wo, bo + l * H_, tmp768, M, H_, H_);
        add_ln_kernel<<<M, blk, 0, stream>>>(x, tmp768, ln1_g + l * H_, ln1_b + l * H_);

        gemm_bias_kernel<1><<<gF, blk, 0, stream>>>(x, w1, b1 + l * FF_, hb, M, H_, FF_);
        gemm_bias_kernel<0><<<gH, blk, 0, stream>>>(hb, w2, b2 + l * H_, tmp768, M, FF_, H_);
        add_ln_kernel<<<M, blk, 0, stream>>>(x, tmp768, ln2_g + l * H_, ln2_b + l * H_);
    }

    qa_kernel<<<M, blk, 0, stream>>>(x, qa_w, qa_b, emis);
    crf_kernel<<<1, 64, 0, stream>>>(emis, attn_mask, start_pos, end_pos,
                                     crf_start, crf_end, crf_trans, out);
}

// Round 2
// 6371.893 us; speedup vs baseline: 2.2282x; 2.2282x over previous
//
#include <hip/hip_runtime.h>
#include <hip/hip_bf16.h>
#include <math.h>

// Problem constants
#define B_  4
#define S_  512
#define H_  768
#define NH_ 12
#define DH_ 64
#define FF_ 3072
#define L_  6
#define V_  30522

// ---------------------------------------------------------------------------
// Embedding gather + LayerNorm.  One block per token (B*S blocks, 256 thr).
// ---------------------------------------------------------------------------
__global__ __launch_bounds__(256) void embed_ln_kernel(
    const int* __restrict__ ids, const int* __restrict__ tt,
    const float* __restrict__ wemb, const float* __restrict__ pemb,
    const float* __restrict__ temb, const float* __restrict__ g,
    const float* __restrict__ bb, float* __restrict__ x)
{
    const int t = blockIdx.x;            // token index in [0, B*S)
    const int s = t % S_;
    const int tid = threadIdx.x;
    __shared__ float red[256];

    const float* wr = wemb + (size_t)ids[t] * H_;
    const float* pr = pemb + (size_t)s * H_;
    const float* tr = temb + (size_t)tt[t] * H_;

    float v[3];
    float sum = 0.f;
#pragma unroll
    for (int i = 0; i < 3; i++) {
        int c = tid + i * 256;
        v[i] = wr[c] + pr[c] + tr[c];
        sum += v[i];
    }
    red[tid] = sum; __syncthreads();
    for (int st = 128; st > 0; st >>= 1) { if (tid < st) red[tid] += red[tid + st]; __syncthreads(); }
    const float mean = red[0] / (float)H_;
    __syncthreads();
    float s2 = 0.f;
#pragma unroll
    for (int i = 0; i < 3; i++) { float d = v[i] - mean; s2 += d * d; }
    red[tid] = s2; __syncthreads();
    for (int st = 128; st > 0; st >>= 1) { if (tid < st) red[tid] += red[tid + st]; __syncthreads(); }
    const float rstd = rsqrtf(red[0] / (float)H_ + 1e-12f);
#pragma unroll
    for (int i = 0; i < 3; i++) {
        int c = tid + i * 256;
        x[(size_t)t * H_ + c] = (v[i] - mean) * rstd * g[c] + bb[c];
    }
}

// ---------------------------------------------------------------------------
// Tiled fp32 GEMM: C[M,N] = A[M,K] @ W[K,N] + bias[N], optional exact GELU.
// BM=BN=64, BK=16, 256 threads, 4x4 per thread.
// ---------------------------------------------------------------------------
#define BM 64
#define BN 64
#define BK 16

template<int EPI>   // 0 = none, 1 = gelu(exact)
__global__ __launch_bounds__(256) void gemm_bias_kernel(
    const float* __restrict__ A, const float* __restrict__ W,
    const float* __restrict__ bias, float* __restrict__ C,
    int M, int K, int N)
{
    __shared__ float As[BK][BM + 1];
    __shared__ float Bs[BK][BN];
    const int tid = threadIdx.x;
    const int tx = tid & 15;      // 0..15 -> n
    const int ty = tid >> 4;      // 0..15 -> m
    const int m0 = blockIdx.y * BM;
    const int n0 = blockIdx.x * BN;

    float acc[4][4] = {};

    for (int k0 = 0; k0 < K; k0 += BK) {
#pragma unroll
        for (int i = 0; i < 4; i++) {
            int lin = tid + i * 256;
            int r = lin >> 4, c = lin & 15;          // r: m-offset, c: k-offset
            As[c][r] = A[(size_t)(m0 + r) * K + k0 + c];
        }
#pragma unroll
        for (int i = 0; i < 4; i++) {
            int lin = tid + i * 256;
            int r = lin >> 6, c = lin & 63;          // r: k-offset, c: n-offset
            Bs[r][c] = W[(size_t)(k0 + r) * N + n0 + c];
        }
        __syncthreads();
#pragma unroll
        for (int kk = 0; kk < BK; kk++) {
            float a[4], w[4];
#pragma unroll
            for (int i = 0; i < 4; i++) a[i] = As[kk][ty * 4 + i];
#pragma unroll
            for (int j = 0; j < 4; j++) w[j] = Bs[kk][tx * 4 + j];
#pragma unroll
            for (int i = 0; i < 4; i++)
#pragma unroll
                for (int j = 0; j < 4; j++)
                    acc[i][j] += a[i] * w[j];
        }
        __syncthreads();
    }

#pragma unroll
    for (int i = 0; i < 4; i++) {
        int m = m0 + ty * 4 + i;
#pragma unroll
        for (int j = 0; j < 4; j++) {
            int n = n0 + tx * 4 + j;
            float v = acc[i][j] + bias[n];
            if (EPI == 1) v = v * 0.5f * (1.0f + erff(v * 0.70710678118654752f));
            C[(size_t)m * N + n] = v;
        }
    }
}

// ---------------------------------------------------------------------------
// Flash-style attention.  One block per (64-query tile, head, batch).
// 256 threads; 4x4 register tile per thread for both QK^T and PV GEMMs.
// Online softmax with 16-lane shuffle row reductions.
// LDS: Qs[d][q] (stride 64), KPs (K as [d][k] then P as [q][k], stride 68),
//      Vs[k][d] (stride 68).  ~53 KB -> 3 blocks/CU.
// ---------------------------------------------------------------------------
__global__ __launch_bounds__(256) void flash_attn_kernel(
    const float* __restrict__ Q, const float* __restrict__ K,
    const float* __restrict__ V, const int* __restrict__ amask,
    float* __restrict__ O)
{
    const int q0 = blockIdx.x * 64;
    const int h  = blockIdx.y;
    const int b  = blockIdx.z;
    const int tid = threadIdx.x;
    const int tx = tid & 15;      // key / d column group
    const int ty = tid >> 4;      // query row group

    __shared__ float Qs[64 * 64];     // Qs[d*64 + q]
    __shared__ float KPs[64 * 68];    // Ks[d*68 + k]  then  Ps[q*68 + k]
    __shared__ float Vs[64 * 68];     // Vs[k*68 + d]
    __shared__ float biasS[S_];

    for (int i = tid; i < S_; i += 256)
        biasS[i] = amask[b * S_ + i] ? 0.f : -1e9f;

    {   // load Q tile transposed (float4 along d)
        const float* qbase = Q + ((size_t)(b * S_ + q0) * H_) + h * DH_;
#pragma unroll
        for (int i = 0; i < 4; i++) {
            int idx = tid + i * 256;               // 0..1023
            int q = idx >> 4, d4 = (idx & 15) * 4;
            float4 v = *(const float4*)(qbase + (size_t)q * H_ + d4);
            Qs[(d4 + 0) * 64 + q] = v.x;
            Qs[(d4 + 1) * 64 + q] = v.y;
            Qs[(d4 + 2) * 64 + q] = v.z;
            Qs[(d4 + 3) * 64 + q] = v.w;
        }
    }

    float acc[4][4] = {};
    float m_i[4], l_i[4];
#pragma unroll
    for (int i = 0; i < 4; i++) { m_i[i] = -INFINITY; l_i[i] = 0.f; }

    for (int kt = 0; kt < S_; kt += 64) {
        __syncthreads();     // previous PV reads of KPs/Vs complete (also covers Q load)
        const float* kbase = K + ((size_t)(b * S_ + kt) * H_) + h * DH_;
        const float* vbase = V + ((size_t)(b * S_ + kt) * H_) + h * DH_;
#pragma unroll
        for (int i = 0; i < 4; i++) {
            int idx = tid + i * 256;
            int kk = idx >> 4, d4 = (idx & 15) * 4;
            float4 v = *(const float4*)(kbase + (size_t)kk * H_ + d4);
            KPs[(d4 + 0) * 68 + kk] = v.x;
            KPs[(d4 + 1) * 68 + kk] = v.y;
            KPs[(d4 + 2) * 68 + kk] = v.z;
            KPs[(d4 + 3) * 68 + kk] = v.w;
            float4 w = *(const float4*)(vbase + (size_t)kk * H_ + d4);
            *(float4*)(&Vs[kk * 68 + d4]) = w;
        }
        __syncthreads();

        // S = (Q K^T) * scale + bias
        float s[4][4] = {};
#pragma unroll 8
        for (int kk = 0; kk < 64; kk++) {
            float a[4], bb[4];
#pragma unroll
            for (int i = 0; i < 4; i++) a[i] = Qs[kk * 64 + ty * 4 + i];
#pragma unroll
            for (int j = 0; j < 4; j++) bb[j] = KPs[kk * 68 + tx * 4 + j];
#pragma unroll
            for (int i = 0; i < 4; i++)
#pragma unroll
                for (int j = 0; j < 4; j++)
                    s[i][j] += a[i] * bb[j];
        }
#pragma unroll
        for (int i = 0; i < 4; i++)
#pragma unroll
            for (int j = 0; j < 4; j++)
                s[i][j] = s[i][j] * 0.125f + biasS[kt + tx * 4 + j];

        // online softmax update (row groups = 16 lanes sharing ty)
        float rs[4];
#pragma unroll
        for (int i = 0; i < 4; i++) {
            float mx = fmaxf(fmaxf(s[i][0], s[i][1]), fmaxf(s[i][2], s[i][3]));
#pragma unroll
            for (int msk = 1; msk < 16; msk <<= 1) mx = fmaxf(mx, __shfl_xor(mx, msk));
            const float newm = fmaxf(m_i[i], mx);
            const float alpha = __expf(m_i[i] - newm);   // -inf-finite -> 0
            m_i[i] = newm;
            float r = 0.f;
#pragma unroll
            for (int j = 0; j < 4; j++) { float p = __expf(s[i][j] - newm); s[i][j] = p; r += p; }
#pragma unroll
            for (int msk = 1; msk < 16; msk <<= 1) r += __shfl_xor(r, msk);
            l_i[i] = l_i[i] * alpha + r;
#pragma unroll
            for (int j = 0; j < 4; j++) acc[i][j] *= alpha;
        }
        (void)rs;

        __syncthreads();     // K reads done; reuse KPs for P
#pragma unroll
        for (int i = 0; i < 4; i++)
            *(float4*)(&KPs[(ty * 4 + i) * 68 + tx * 4]) =
                make_float4(s[i][0], s[i][1], s[i][2], s[i][3]);
        __syncthreads();

        // O += P V
#pragma unroll 8
        for (int kk = 0; kk < 64; kk++) {
            float a[4], bb[4];
#pragma unroll
            for (int i = 0; i < 4; i++) a[i] = KPs[(ty * 4 + i) * 68 + kk];
#pragma unroll
            for (int j = 0; j < 4; j++) bb[j] = Vs[kk * 68 + tx * 4 + j];
#pragma unroll
            for (int i = 0; i < 4; i++)
#pragma unroll
                for (int j = 0; j < 4; j++)
                    acc[i][j] += a[i] * bb[j];
        }
    }

    float* obase = O + ((size_t)(b * S_ + q0) * H_) + h * DH_;
#pragma unroll
    for (int i = 0; i < 4; i++) {
        const float invl = 1.0f / l_i[i];
        *(float4*)(obase + (size_t)(ty * 4 + i) * H_ + tx * 4) =
            make_float4(acc[i][0] * invl, acc[i][1] * invl,
                        acc[i][2] * invl, acc[i][3] * invl);
    }
}

// ---------------------------------------------------------------------------
// x = LN(x + delta), per-token block, in place.
// ---------------------------------------------------------------------------
__global__ __launch_bounds__(256) void add_ln_kernel(
    float* __restrict__ x, const float* __restrict__ delta,
    const float* __restrict__ g, const float* __restrict__ bb)
{
    const int t = blockIdx.x;
    const int tid = threadIdx.x;
    __shared__ float red[256];
    const size_t base = (size_t)t * H_;

    float v[3];
    float sum = 0.f;
#pragma unroll
    for (int i = 0; i < 3; i++) {
        int c = tid + i * 256;
        v[i] = x[base + c] + delta[base + c];
        sum += v[i];
    }
    red[tid] = sum; __syncthreads();
    for (int st = 128; st > 0; st >>= 1) { if (tid < st) red[tid] += red[tid + st]; __syncthreads(); }
    const float mean = red[0] / (float)H_;
    __syncthreads();
    float s2 = 0.f;
#pragma unroll
    for (int i = 0; i < 3; i++) { float d = v[i] - mean; s2 += d * d; }
    red[tid] = s2; __syncthreads();
    for (int st = 128; st > 0; st >>= 1) { if (tid < st) red[tid] += red[tid + st]; __syncthreads(); }
    const float rstd = rsqrtf(red[0] / (float)H_ + 1e-12f);
#pragma unroll
    for (int i = 0; i < 3; i++) {
        int c = tid + i * 256;
        x[base + c] = (v[i] - mean) * rstd * g[c] + bb[c];
    }
}

// ---------------------------------------------------------------------------
// QA head: emissions[t, 0..1] = x[t,:] @ qa_w + qa_b.  One block per token.
// ---------------------------------------------------------------------------
__global__ __launch_bounds__(256) void qa_kernel(
    const float* __restrict__ x, const float* __restrict__ qa_w,
    const float* __restrict__ qa_b, float* __restrict__ em)
{
    const int t = blockIdx.x;
    const int tid = threadIdx.x;
    __shared__ float r0[256], r1[256];
    float s0 = 0.f, s1 = 0.f;
#pragma unroll
    for (int i = 0; i < 3; i++) {
        int c = tid + i * 256;
        float xv = x[(size_t)t * H_ + c];
        s0 += xv * qa_w[c * 2 + 0];
        s1 += xv * qa_w[c * 2 + 1];
    }
    r0[tid] = s0; r1[tid] = s1; __syncthreads();
    for (int st = 128; st > 0; st >>= 1) {
        if (tid < st) { r0[tid] += r0[tid + st]; r1[tid] += r1[tid + st]; }
        __syncthreads();
    }
    if (tid == 0) {
        em[(size_t)t * 2 + 0] = r0[0] + qa_b[0];
        em[(size_t)t * 2 + 1] = r1[0] + qa_b[1];
    }
}

// ---------------------------------------------------------------------------
// CRF: one block; lane b < 4 handles one sequence serially (2 tags, S=512).
// ---------------------------------------------------------------------------
__device__ __forceinline__ float lse2(float a, float b) {
    float m = fmaxf(a, b);
    return m + log1pf(expf(-fabsf(a - b)));
}

__global__ void crf_kernel(
    const float* __restrict__ em, const int* __restrict__ amask,
    const int* __restrict__ spos, const int* __restrict__ epos,
    const float* __restrict__ startT, const float* __restrict__ endT,
    const float* __restrict__ trans, float* __restrict__ out)
{
    __shared__ float partial[B_];
    const int b = threadIdx.x;
    if (b < B_) {
        const int sp = spos[b], ep = epos[b];
        const bool valid = (sp >= 0) && (sp < S_) && (ep >= 0) && (ep < S_) && (sp <= ep);
        const float* e = em + (size_t)b * S_ * 2;
        const int* mk = amask + b * S_;
        const float t00 = trans[0], t01 = trans[1], t10 = trans[2], t11 = trans[3];

        int prev = (valid && 0 >= sp && 0 <= ep) ? 1 : 0;
        float num = startT[prev] + e[prev];
        float a0 = startT[0] + e[0];
        float a1 = startT[1] + e[1];
        int msum = mk[0] ? 1 : 0;

        for (int t = 1; t < S_; t++) {
            const int cur = (valid && t >= sp && t <= ep) ? 1 : 0;
            const float e0 = e[t * 2 + 0], e1 = e[t * 2 + 1];
            const float mf = mk[t] ? 1.f : 0.f;
            const float tr = prev ? (cur ? t11 : t10) : (cur ? t01 : t00);
            num += (tr + (cur ? e1 : e0)) * mf;
            const float n0 = lse2(a0 + t00, a1 + t10) + e0;
            const float n1 = lse2(a0 + t01, a1 + t11) + e1;
            if (mk[t]) { a0 = n0; a1 = n1; }
            msum += mk[t] ? 1 : 0;
            prev = cur;
        }
        const int last_idx = msum - 1;
        const int last_lab = (valid && last_idx >= sp && last_idx <= ep) ? 1 : 0;
        num += endT[last_lab];
        const float logZ = lse2(a0 + endT[0], a1 + endT[1]);
        partial[b] = num - logZ;
    }
    __syncthreads();
    if (threadIdx.x == 0)
        out[0] = -(partial[0] + partial[1] + partial[2] + partial[3]);
}

// ---------------------------------------------------------------------------
// Launch
// ---------------------------------------------------------------------------
extern "C" void kernel_launch(void* const* d_in, const int* in_sizes, int n_in,
                              void* d_out, int out_size, void* d_ws, size_t ws_size,
                              hipStream_t stream)
{
    const int*   input_ids  = (const int*)  d_in[0];
    const int*   attn_mask  = (const int*)  d_in[1];
    const int*   token_type = (const int*)  d_in[2];
    const int*   start_pos  = (const int*)  d_in[3];
    const int*   end_pos    = (const int*)  d_in[4];
    const float* word_emb   = (const float*)d_in[5];
    const float* pos_emb    = (const float*)d_in[6];
    const float* type_emb   = (const float*)d_in[7];
    const float* emb_ln_g   = (const float*)d_in[8];
    const float* emb_ln_b   = (const float*)d_in[9];
    const float* Wq         = (const float*)d_in[10];
    const float* bq         = (const float*)d_in[11];
    const float* Wk         = (const float*)d_in[12];
    const float* bk         = (const float*)d_in[13];
    const float* Wv         = (const float*)d_in[14];
    const float* bv         = (const float*)d_in[15];
    const float* Wo         = (const float*)d_in[16];
    const float* bo         = (const float*)d_in[17];
    const float* ln1_g      = (const float*)d_in[18];
    const float* ln1_b      = (const float*)d_in[19];
    const float* W1         = (const float*)d_in[20];
    const float* b1         = (const float*)d_in[21];
    const float* W2         = (const float*)d_in[22];
    const float* b2         = (const float*)d_in[23];
    const float* ln2_g      = (const float*)d_in[24];
    const float* ln2_b      = (const float*)d_in[25];
    const float* qa_w       = (const float*)d_in[26];
    const float* qa_b       = (const float*)d_in[27];
    const float* crf_start  = (const float*)d_in[28];
    const float* crf_end    = (const float*)d_in[29];
    const float* crf_trans  = (const float*)d_in[30];
    float* out = (float*)d_out;

    const int M = B_ * S_;                 // 2048 tokens
    float* ws  = (float*)d_ws;
    float* x      = ws;
    float* scr    = x + (size_t)M * H_;            // M*FF floats
    float* tmp768 = scr + (size_t)M * FF_;
    float* emis   = tmp768 + (size_t)M * H_;
    float* qb  = scr;
    float* kb  = qb + (size_t)M * H_;
    float* vb  = kb + (size_t)M * H_;
    float* ctx = vb + (size_t)M * H_;
    float* hb  = scr;                               // aliases q/k/v/ctx (disjoint in time)

    dim3 blk(256);

    embed_ln_kernel<<<M, blk, 0, stream>>>(input_ids, token_type, word_emb, pos_emb,
                                           type_emb, emb_ln_g, emb_ln_b, x);

    const dim3 gH(H_ / BN, M / BM);    // GEMM grid for N=768
    const dim3 gF(FF_ / BN, M / BM);   // GEMM grid for N=3072
    const dim3 gA(S_ / 64, NH_, B_);   // flash attention grid

    for (int l = 0; l < L_; l++) {
        const float* wq = Wq + (size_t)l * H_ * H_;
        const float* wk = Wk + (size_t)l * H_ * H_;
        const float* wv = Wv + (size_t)l * H_ * H_;
        const float* wo = Wo + (size_t)l * H_ * H_;
        const float* w1 = W1 + (size_t)l * H_ * FF_;
        const float* w2 = W2 + (size_t)l * FF_ * H_;

        gemm_bias_kernel<0><<<gH, blk, 0, stream>>>(x, wq, bq + l * H_, qb, M, H_, H_);
        gemm_bias_kernel<0><<<gH, blk, 0, stream>>>(x, wk, bk + l * H_, kb, M, H_, H_);
        gemm_bias_kernel<0><<<gH, blk, 0, stream>>>(x, wv, bv + l * H_, vb, M, H_, H_);

        flash_attn_kernel<<<gA, blk, 0, stream>>>(qb, kb, vb, attn_mask, ctx);

        gemm_bias_kernel<0><<<gH, blk, 0, stream>>>(ctx, wo, bo + l * H_, tmp768, M, H_, H_);
        add_ln_kernel<<<M, blk, 0, stream>>>(x, tmp768, ln1_g + l * H_, ln1_b + l * H_);

        gemm_bias_kernel<1><<<gF, blk, 0, stream>>>(x, w1, b1 + l * FF_, hb, M, H_, FF_);
        gemm_bias_kernel<0><<<gH, blk, 0, stream>>>(hb, w2, b2 + l * H_, tmp768, M, FF_, H_);
        add_ln_kernel<<<M, blk, 0, stream>>>(x, tmp768, ln2_g + l * H_, ln2_b + l * H_);
    }

    qa_kernel<<<M, blk, 0, stream>>>(x, qa_w, qa_b, emis);
    crf_kernel<<<1, 64, 0, stream>>>(emis, attn_mask, start_pos, end_pos,
                                     crf_start, crf_end, crf_trans, out);
}

// Round 3
// 2015.057 us; speedup vs baseline: 7.0459x; 3.1621x over previous
//
#include <hip/hip_runtime.h>
#include <hip/hip_bf16.h>
#include <math.h>

// Problem constants
#define B_  4
#define S_  512
#define H_  768
#define NH_ 12
#define DH_ 64
#define FF_ 3072
#define L_  6
#define V_  30522
#define QKVN 2304          // fused QKV output width
#define M_  (B_ * S_)      // 2048 tokens

typedef short s16x8 __attribute__((ext_vector_type(8)));
typedef float f32x4 __attribute__((ext_vector_type(4)));

__device__ __forceinline__ void gload_lds16(const void* g, void* l) {
    __builtin_amdgcn_global_load_lds(
        (const __attribute__((address_space(1))) void*)g,
        (__attribute__((address_space(3))) void*)l,
        16, 0, 0);
}

// ---------------------------------------------------------------------------
// Embedding gather + LayerNorm -> x (fp32) and xb (bf16 shadow).
// ---------------------------------------------------------------------------
__global__ __launch_bounds__(256) void embed_ln_kernel(
    const int* __restrict__ ids, const int* __restrict__ tt,
    const float* __restrict__ wemb, const float* __restrict__ pemb,
    const float* __restrict__ temb, const float* __restrict__ g,
    const float* __restrict__ bb, float* __restrict__ x,
    __hip_bfloat16* __restrict__ xb)
{
    const int t = blockIdx.x;
    const int s = t % S_;
    const int tid = threadIdx.x;
    __shared__ float red[256];

    const float* wr = wemb + (size_t)ids[t] * H_;
    const float* pr = pemb + (size_t)s * H_;
    const float* tr = temb + (size_t)tt[t] * H_;

    float v[3];
    float sum = 0.f;
#pragma unroll
    for (int i = 0; i < 3; i++) {
        int c = tid + i * 256;
        v[i] = wr[c] + pr[c] + tr[c];
        sum += v[i];
    }
    red[tid] = sum; __syncthreads();
    for (int st = 128; st > 0; st >>= 1) { if (tid < st) red[tid] += red[tid + st]; __syncthreads(); }
    const float mean = red[0] / (float)H_;
    __syncthreads();
    float s2 = 0.f;
#pragma unroll
    for (int i = 0; i < 3; i++) { float d = v[i] - mean; s2 += d * d; }
    red[tid] = s2; __syncthreads();
    for (int st = 128; st > 0; st >>= 1) { if (tid < st) red[tid] += red[tid + st]; __syncthreads(); }
    const float rstd = rsqrtf(red[0] / (float)H_ + 1e-12f);
#pragma unroll
    for (int i = 0; i < 3; i++) {
        int c = tid + i * 256;
        float o = (v[i] - mean) * rstd * g[c] + bb[c];
        x[(size_t)t * H_ + c] = o;
        xb[(size_t)t * H_ + c] = __float2bfloat16(o);
    }
}

// ---------------------------------------------------------------------------
// Weight transpose + fp32->bf16 convert: W[K][N] row-major -> Wt[N][K] bf16.
// 32x32 LDS tile, grid (N/32, K/32), block (32,8).
// ---------------------------------------------------------------------------
__global__ __launch_bounds__(256) void transpose_bf16_kernel(
    const float* __restrict__ W, __hip_bfloat16* __restrict__ Wt, int K, int N)
{
    __shared__ float tile[32][33];
    const int tx = threadIdx.x;   // 0..31
    const int ty = threadIdx.y;   // 0..7
    const int n0 = blockIdx.x * 32;
    const int k0 = blockIdx.y * 32;
#pragma unroll
    for (int i = 0; i < 4; i++)
        tile[ty + 8 * i][tx] = W[(size_t)(k0 + ty + 8 * i) * N + n0 + tx];
    __syncthreads();
#pragma unroll
    for (int i = 0; i < 4; i++)
        Wt[(size_t)(n0 + ty + 8 * i) * K + k0 + tx] =
            __float2bfloat16(tile[tx][ty + 8 * i]);
}

// Concatenate bq|bk|bv into b_qkv[2304]
__global__ void concat3_kernel(const float* __restrict__ a, const float* __restrict__ b,
                               const float* __restrict__ c, float* __restrict__ out)
{
    int i = blockIdx.x * 256 + threadIdx.x;
    if (i < QKVN)
        out[i] = (i < H_) ? a[i] : ((i < 2 * H_) ? b[i - H_] : c[i - 2 * H_]);
}

// ---------------------------------------------------------------------------
// bf16 MFMA GEMM (m97 structure): C[M][N] = A[M][K] @ Bt[N][K]^T + bias.
// 128x128 tile, BK=32, 256 thr = 4 waves (2x2 of 64x64), 16x16x32 MFMA.
// A, Bt bf16; accumulate fp32.  EPI: 0=none 1=exact gelu.  OUTBF: bf16 out.
// ---------------------------------------------------------------------------
#define TM 128
#define TN 128
#define TK 32

template<int EPI, int OUTBF>
__global__ __launch_bounds__(256) void gemm_mfma_kernel(
    const ushort* __restrict__ A, const ushort* __restrict__ Bt,
    const float* __restrict__ bias, void* __restrict__ Cout,
    int M, int K, int N)
{
    __shared__ ushort As[TM * TK];   // [m][k], row stride 32 (64B)
    __shared__ ushort Bs[TN * TK];   // [n][k]
    const int tid  = threadIdx.x;
    const int lane = tid & 63;
    const int wave = tid >> 6;
    const int m0 = blockIdx.y * TM;
    const int n0 = blockIdx.x * TN;
    const int wm = (wave >> 1) * 64;
    const int wn = (wave & 1) * 64;

    f32x4 acc[4][4];
#pragma unroll
    for (int i = 0; i < 4; i++)
#pragma unroll
        for (int j = 0; j < 4; j++)
            acc[i][j] = (f32x4){0.f, 0.f, 0.f, 0.f};

    // staging: wave w stages 1KB chunks {2w, 2w+1} of A and of B.
    // chunk c = rows c*16..c*16+15 (16 rows x 32 k).  lane i -> row c*16+(i>>2),
    // k-offset (i&3)*8; LDS dest = chunk base + lane*16B  (row-major [r][k]).
    const int c0 = wave * 2;
    const int rr = lane >> 2;
    const int ko = (lane & 3) * 8;
    const ushort* aS0 = A  + (size_t)(m0 + c0 * 16 + rr)       * K + ko;
    const ushort* aS1 = A  + (size_t)(m0 + (c0 + 1) * 16 + rr) * K + ko;
    const ushort* bS0 = Bt + (size_t)(n0 + c0 * 16 + rr)       * K + ko;
    const ushort* bS1 = Bt + (size_t)(n0 + (c0 + 1) * 16 + rr) * K + ko;
    ushort* aD0 = &As[(c0 * 16) * TK];
    ushort* aD1 = &As[((c0 + 1) * 16) * TK];
    ushort* bD0 = &Bs[(c0 * 16) * TK];
    ushort* bD1 = &Bs[((c0 + 1) * 16) * TK];

    const int fr = lane & 15;          // fragment row (m or n)
    const int fk = (lane >> 4) * 8;    // fragment k offset

    for (int k0 = 0; k0 < K; k0 += TK) {
        __syncthreads();               // prior ds_reads done before overwrite
        gload_lds16(aS0 + k0, aD0);
        gload_lds16(aS1 + k0, aD1);
        gload_lds16(bS0 + k0, bD0);
        gload_lds16(bS1 + k0, bD1);
        __syncthreads();               // staging visible

        s16x8 af[4], bf[4];
#pragma unroll
        for (int i = 0; i < 4; i++)
            af[i] = *(const s16x8*)&As[(wm + i * 16 + fr) * TK + fk];
#pragma unroll
        for (int j = 0; j < 4; j++)
            bf[j] = *(const s16x8*)&Bs[(wn + j * 16 + fr) * TK + fk];
#pragma unroll
        for (int i = 0; i < 4; i++)
#pragma unroll
            for (int j = 0; j < 4; j++)
                acc[i][j] = __builtin_amdgcn_mfma_f32_16x16x32_bf16(
                    af[i], bf[j], acc[i][j], 0, 0, 0);
    }

    // epilogue: C/D layout col=lane&15, row=(lane>>4)*4+reg
    const int ecol = lane & 15;
    const int erow = (lane >> 4) * 4;
#pragma unroll
    for (int j = 0; j < 4; j++) {
        const int gcol = n0 + wn + j * 16 + ecol;
        const float bv = bias[gcol];
#pragma unroll
        for (int i = 0; i < 4; i++) {
#pragma unroll
            for (int r = 0; r < 4; r++) {
                const int grow = m0 + wm + i * 16 + erow + r;
                float v = acc[i][j][r] + bv;
                if (EPI == 1) v = v * 0.5f * (1.0f + erff(v * 0.70710678118654752f));
                if (OUTBF)
                    ((__hip_bfloat16*)Cout)[(size_t)grow * N + gcol] = __float2bfloat16(v);
                else
                    ((float*)Cout)[(size_t)grow * N + gcol] = v;
            }
        }
    }
}

// ---------------------------------------------------------------------------
// Flash-style attention over fused QKV (fp32, row stride 2304).
// One block per (64-query tile, head, batch); writes ctx as bf16.
// ---------------------------------------------------------------------------
__global__ __launch_bounds__(256) void flash_attn_kernel(
    const float* __restrict__ QKV, const int* __restrict__ amask,
    __hip_bfloat16* __restrict__ O)
{
    const int q0 = blockIdx.x * 64;
    const int h  = blockIdx.y;
    const int b  = blockIdx.z;
    const int tid = threadIdx.x;
    const int tx = tid & 15;
    const int ty = tid >> 4;

    __shared__ float Qs[64 * 64];     // Qs[d*64 + q]
    __shared__ float KPs[64 * 68];    // Ks[d*68 + k]  then  Ps[q*68 + k]
    __shared__ float Vs[64 * 68];     // Vs[k*68 + d]
    __shared__ float biasS[S_];

    for (int i = tid; i < S_; i += 256)
        biasS[i] = amask[b * S_ + i] ? 0.f : -1e9f;

    {
        const float* qbase = QKV + (size_t)(b * S_ + q0) * QKVN + h * DH_;
#pragma unroll
        for (int i = 0; i < 4; i++) {
            int idx = tid + i * 256;
            int q = idx >> 4, d4 = (idx & 15) * 4;
            float4 v = *(const float4*)(qbase + (size_t)q * QKVN + d4);
            Qs[(d4 + 0) * 64 + q] = v.x;
            Qs[(d4 + 1) * 64 + q] = v.y;
            Qs[(d4 + 2) * 64 + q] = v.z;
            Qs[(d4 + 3) * 64 + q] = v.w;
        }
    }

    float acc[4][4] = {};
    float m_i[4], l_i[4];
#pragma unroll
    for (int i = 0; i < 4; i++) { m_i[i] = -INFINITY; l_i[i] = 0.f; }

    for (int kt = 0; kt < S_; kt += 64) {
        __syncthreads();
        const float* kbase = QKV + (size_t)(b * S_ + kt) * QKVN + H_ + h * DH_;
        const float* vbase = QKV + (size_t)(b * S_ + kt) * QKVN + 2 * H_ + h * DH_;
#pragma unroll
        for (int i = 0; i < 4; i++) {
            int idx = tid + i * 256;
            int kk = idx >> 4, d4 = (idx & 15) * 4;
            float4 v = *(const float4*)(kbase + (size_t)kk * QKVN + d4);
            KPs[(d4 + 0) * 68 + kk] = v.x;
            KPs[(d4 + 1) * 68 + kk] = v.y;
            KPs[(d4 + 2) * 68 + kk] = v.z;
            KPs[(d4 + 3) * 68 + kk] = v.w;
            float4 w = *(const float4*)(vbase + (size_t)kk * QKVN + d4);
            *(float4*)(&Vs[kk * 68 + d4]) = w;
        }
        __syncthreads();

        float s[4][4] = {};
#pragma unroll 8
        for (int kk = 0; kk < 64; kk++) {
            float a[4], bb[4];
#pragma unroll
            for (int i = 0; i < 4; i++) a[i] = Qs[kk * 64 + ty * 4 + i];
#pragma unroll
            for (int j = 0; j < 4; j++) bb[j] = KPs[kk * 68 + tx * 4 + j];
#pragma unroll
            for (int i = 0; i < 4; i++)
#pragma unroll
                for (int j = 0; j < 4; j++)
                    s[i][j] += a[i] * bb[j];
        }
#pragma unroll
        for (int i = 0; i < 4; i++)
#pragma unroll
            for (int j = 0; j < 4; j++)
                s[i][j] = s[i][j] * 0.125f + biasS[kt + tx * 4 + j];

#pragma unroll
        for (int i = 0; i < 4; i++) {
            float mx = fmaxf(fmaxf(s[i][0], s[i][1]), fmaxf(s[i][2], s[i][3]));
#pragma unroll
            for (int msk = 1; msk < 16; msk <<= 1) mx = fmaxf(mx, __shfl_xor(mx, msk));
            const float newm = fmaxf(m_i[i], mx);
            const float alpha = __expf(m_i[i] - newm);
            m_i[i] = newm;
            float r = 0.f;
#pragma unroll
            for (int j = 0; j < 4; j++) { float p = __expf(s[i][j] - newm); s[i][j] = p; r += p; }
#pragma unroll
            for (int msk = 1; msk < 16; msk <<= 1) r += __shfl_xor(r, msk);
            l_i[i] = l_i[i] * alpha + r;
#pragma unroll
            for (int j = 0; j < 4; j++) acc[i][j] *= alpha;
        }

        __syncthreads();
#pragma unroll
        for (int i = 0; i < 4; i++)
            *(float4*)(&KPs[(ty * 4 + i) * 68 + tx * 4]) =
                make_float4(s[i][0], s[i][1], s[i][2], s[i][3]);
        __syncthreads();

#pragma unroll 8
        for (int kk = 0; kk < 64; kk++) {
            float a[4], bb[4];
#pragma unroll
            for (int i = 0; i < 4; i++) a[i] = KPs[(ty * 4 + i) * 68 + kk];
#pragma unroll
            for (int j = 0; j < 4; j++) bb[j] = Vs[kk * 68 + tx * 4 + j];
#pragma unroll
            for (int i = 0; i < 4; i++)
#pragma unroll
                for (int j = 0; j < 4; j++)
                    acc[i][j] += a[i] * bb[j];
        }
    }

    __hip_bfloat16* obase = O + ((size_t)(b * S_ + q0) * H_) + h * DH_;
#pragma unroll
    for (int i = 0; i < 4; i++) {
        const float invl = 1.0f / l_i[i];
        __hip_bfloat16* op = obase + (size_t)(ty * 4 + i) * H_ + tx * 4;
        op[0] = __float2bfloat16(acc[i][0] * invl);
        op[1] = __float2bfloat16(acc[i][1] * invl);
        op[2] = __float2bfloat16(acc[i][2] * invl);
        op[3] = __float2bfloat16(acc[i][3] * invl);
    }
}

// ---------------------------------------------------------------------------
// x = LN(x + delta) in place; also writes bf16 shadow xb.
// ---------------------------------------------------------------------------
__global__ __launch_bounds__(256) void add_ln_kernel(
    float* __restrict__ x, const float* __restrict__ delta,
    const float* __restrict__ g, const float* __restrict__ bb,
    __hip_bfloat16* __restrict__ xb)
{
    const int t = blockIdx.x;
    const int tid = threadIdx.x;
    __shared__ float red[256];
    const size_t base = (size_t)t * H_;

    float v[3];
    float sum = 0.f;
#pragma unroll
    for (int i = 0; i < 3; i++) {
        int c = tid + i * 256;
        v[i] = x[base + c] + delta[base + c];
        sum += v[i];
    }
    red[tid] = sum; __syncthreads();
    for (int st = 128; st > 0; st >>= 1) { if (tid < st) red[tid] += red[tid + st]; __syncthreads(); }
    const float mean = red[0] / (float)H_;
    __syncthreads();
    float s2 = 0.f;
#pragma unroll
    for (int i = 0; i < 3; i++) { float d = v[i] - mean; s2 += d * d; }
    red[tid] = s2; __syncthreads();
    for (int st = 128; st > 0; st >>= 1) { if (tid < st) red[tid] += red[tid + st]; __syncthreads(); }
    const float rstd = rsqrtf(red[0] / (float)H_ + 1e-12f);
#pragma unroll
    for (int i = 0; i < 3; i++) {
        int c = tid + i * 256;
        float o = (v[i] - mean) * rstd * g[c] + bb[c];
        x[base + c] = o;
        xb[base + c] = __float2bfloat16(o);
    }
}

// ---------------------------------------------------------------------------
// QA head: emissions[t,0..1] = x[t,:] @ qa_w + qa_b.
// ---------------------------------------------------------------------------
__global__ __launch_bounds__(256) void qa_kernel(
    const float* __restrict__ x, const float* __restrict__ qa_w,
    const float* __restrict__ qa_b, float* __restrict__ em)
{
    const int t = blockIdx.x;
    const int tid = threadIdx.x;
    __shared__ float r0[256], r1[256];
    float s0 = 0.f, s1 = 0.f;
#pragma unroll
    for (int i = 0; i < 3; i++) {
        int c = tid + i * 256;
        float xv = x[(size_t)t * H_ + c];
        s0 += xv * qa_w[c * 2 + 0];
        s1 += xv * qa_w[c * 2 + 1];
    }
    r0[tid] = s0; r1[tid] = s1; __syncthreads();
    for (int st = 128; st > 0; st >>= 1) {
        if (tid < st) { r0[tid] += r0[tid + st]; r1[tid] += r1[tid + st]; }
        __syncthreads();
    }
    if (tid == 0) {
        em[(size_t)t * 2 + 0] = r0[0] + qa_b[0];
        em[(size_t)t * 2 + 1] = r1[0] + qa_b[1];
    }
}

// ---------------------------------------------------------------------------
// CRF (unchanged)
// ---------------------------------------------------------------------------
__device__ __forceinline__ float lse2(float a, float b) {
    float m = fmaxf(a, b);
    return m + log1pf(expf(-fabsf(a - b)));
}

__global__ void crf_kernel(
    const float* __restrict__ em, const int* __restrict__ amask,
    const int* __restrict__ spos, const int* __restrict__ epos,
    const float* __restrict__ startT, const float* __restrict__ endT,
    const float* __restrict__ trans, float* __restrict__ out)
{
    __shared__ float partial[B_];
    const int b = threadIdx.x;
    if (b < B_) {
        const int sp = spos[b], ep = epos[b];
        const bool valid = (sp >= 0) && (sp < S_) && (ep >= 0) && (ep < S_) && (sp <= ep);
        const float* e = em + (size_t)b * S_ * 2;
        const int* mk = amask + b * S_;
        const float t00 = trans[0], t01 = trans[1], t10 = trans[2], t11 = trans[3];

        int prev = (valid && 0 >= sp && 0 <= ep) ? 1 : 0;
        float num = startT[prev] + e[prev];
        float a0 = startT[0] + e[0];
        float a1 = startT[1] + e[1];
        int msum = mk[0] ? 1 : 0;

        for (int t = 1; t < S_; t++) {
            const int cur = (valid && t >= sp && t <= ep) ? 1 : 0;
            const float e0 = e[t * 2 + 0], e1 = e[t * 2 + 1];
            const float mf = mk[t] ? 1.f : 0.f;
            const float tr = prev ? (cur ? t11 : t10) : (cur ? t01 : t00);
            num += (tr + (cur ? e1 : e0)) * mf;
            const float n0 = lse2(a0 + t00, a1 + t10) + e0;
            const float n1 = lse2(a0 + t01, a1 + t11) + e1;
            if (mk[t]) { a0 = n0; a1 = n1; }
            msum += mk[t] ? 1 : 0;
            prev = cur;
        }
        const int last_idx = msum - 1;
        const int last_lab = (valid && last_idx >= sp && last_idx <= ep) ? 1 : 0;
        num += endT[last_lab];
        const float logZ = lse2(a0 + endT[0], a1 + endT[1]);
        partial[b] = num - logZ;
    }
    __syncthreads();
    if (threadIdx.x == 0)
        out[0] = -(partial[0] + partial[1] + partial[2] + partial[3]);
}

// ---------------------------------------------------------------------------
// Launch
// ---------------------------------------------------------------------------
extern "C" void kernel_launch(void* const* d_in, const int* in_sizes, int n_in,
                              void* d_out, int out_size, void* d_ws, size_t ws_size,
                              hipStream_t stream)
{
    const int*   input_ids  = (const int*)  d_in[0];
    const int*   attn_mask  = (const int*)  d_in[1];
    const int*   token_type = (const int*)  d_in[2];
    const int*   start_pos  = (const int*)  d_in[3];
    const int*   end_pos    = (const int*)  d_in[4];
    const float* word_emb   = (const float*)d_in[5];
    const float* pos_emb    = (const float*)d_in[6];
    const float* type_emb   = (const float*)d_in[7];
    const float* emb_ln_g   = (const float*)d_in[8];
    const float* emb_ln_b   = (const float*)d_in[9];
    const float* Wq         = (const float*)d_in[10];
    const float* bq         = (const float*)d_in[11];
    const float* Wk         = (const float*)d_in[12];
    const float* bk         = (const float*)d_in[13];
    const float* Wv         = (const float*)d_in[14];
    const float* bv         = (const float*)d_in[15];
    const float* Wo         = (const float*)d_in[16];
    const float* bo         = (const float*)d_in[17];
    const float* ln1_g      = (const float*)d_in[18];
    const float* ln1_b      = (const float*)d_in[19];
    const float* W1         = (const float*)d_in[20];
    const float* b1         = (const float*)d_in[21];
    const float* W2         = (const float*)d_in[22];
    const float* b2         = (const float*)d_in[23];
    const float* ln2_g      = (const float*)d_in[24];
    const float* ln2_b      = (const float*)d_in[25];
    const float* qa_w       = (const float*)d_in[26];
    const float* qa_b       = (const float*)d_in[27];
    const float* crf_start  = (const float*)d_in[28];
    const float* crf_end    = (const float*)d_in[29];
    const float* crf_trans  = (const float*)d_in[30];
    float* out = (float*)d_out;

    // Workspace carve-up (~65 MB)
    float*          x      = (float*)d_ws;                         // M*H fp32
    __hip_bfloat16* xb     = (__hip_bfloat16*)(x + (size_t)M_ * H_);      // M*H
    float*          qkv    = (float*)(xb + (size_t)M_ * H_);              // M*2304
    __hip_bfloat16* ctxb   = (__hip_bfloat16*)(qkv + (size_t)M_ * QKVN);  // M*H
    __hip_bfloat16* hb     = ctxb + (size_t)M_ * H_;                      // M*FF
    float*          tmp768 = (float*)(hb + (size_t)M_ * FF_);             // M*H
    float*          emis   = tmp768 + (size_t)M_ * H_;                    // M*2
    float*          b_qkv  = emis + (size_t)M_ * 2;                       // 2304
    __hip_bfloat16* Wt_qkv = (__hip_bfloat16*)(b_qkv + QKVN);             // 2304*768
    __hip_bfloat16* Wt_o   = Wt_qkv + (size_t)QKVN * H_;                  // 768*768
    __hip_bfloat16* Wt_1   = Wt_o + (size_t)H_ * H_;                      // 3072*768
    __hip_bfloat16* Wt_2   = Wt_1 + (size_t)FF_ * H_;                     // 768*3072

    dim3 blk(256);
    dim3 tblk(32, 8);

    embed_ln_kernel<<<M_, blk, 0, stream>>>(input_ids, token_type, word_emb, pos_emb,
                                            type_emb, emb_ln_g, emb_ln_b, x, xb);

    const dim3 gQKV(QKVN / TN, M_ / TM);   // 18 x 16
    const dim3 gO(H_ / TN, M_ / TM);       // 6 x 16
    const dim3 gF1(FF_ / TN, M_ / TM);     // 24 x 16
    const dim3 gA(S_ / 64, NH_, B_);

    for (int l = 0; l < L_; l++) {
        const float* wq = Wq + (size_t)l * H_ * H_;
        const float* wk = Wk + (size_t)l * H_ * H_;
        const float* wv = Wv + (size_t)l * H_ * H_;
        const float* wo = Wo + (size_t)l * H_ * H_;
        const float* w1 = W1 + (size_t)l * H_ * FF_;
        const float* w2 = W2 + (size_t)l * FF_ * H_;

        // weight prep (transpose + bf16)
        transpose_bf16_kernel<<<dim3(24, 24), tblk, 0, stream>>>(wq, Wt_qkv, H_, H_);
        transpose_bf16_kernel<<<dim3(24, 24), tblk, 0, stream>>>(wk, Wt_qkv + (size_t)H_ * H_, H_, H_);
        transpose_bf16_kernel<<<dim3(24, 24), tblk, 0, stream>>>(wv, Wt_qkv + (size_t)2 * H_ * H_, H_, H_);
        concat3_kernel<<<9, 256, 0, stream>>>(bq + l * H_, bk + l * H_, bv + l * H_, b_qkv);
        transpose_bf16_kernel<<<dim3(24, 24), tblk, 0, stream>>>(wo, Wt_o, H_, H_);
        transpose_bf16_kernel<<<dim3(96, 24), tblk, 0, stream>>>(w1, Wt_1, H_, FF_);
        transpose_bf16_kernel<<<dim3(24, 96), tblk, 0, stream>>>(w2, Wt_2, FF_, H_);

        // fused QKV projection
        gemm_mfma_kernel<0, 0><<<gQKV, blk, 0, stream>>>(
            (const ushort*)xb, (const ushort*)Wt_qkv, b_qkv, qkv, M_, H_, QKVN);

        flash_attn_kernel<<<gA, blk, 0, stream>>>(qkv, attn_mask, ctxb);

        gemm_mfma_kernel<0, 0><<<gO, blk, 0, stream>>>(
            (const ushort*)ctxb, (const ushort*)Wt_o, bo + l * H_, tmp768, M_, H_, H_);
        add_ln_kernel<<<M_, blk, 0, stream>>>(x, tmp768, ln1_g + l * H_, ln1_b + l * H_, xb);

        gemm_mfma_kernel<1, 1><<<gF1, blk, 0, stream>>>(
            (const ushort*)xb, (const ushort*)Wt_1, b1 + l * FF_, hb, M_, H_, FF_);
        gemm_mfma_kernel<0, 0><<<gO, blk, 0, stream>>>(
            (const ushort*)hb, (const ushort*)Wt_2, b2 + l * H_, tmp768, M_, FF_, H_);
        add_ln_kernel<<<M_, blk, 0, stream>>>(x, tmp768, ln2_g + l * H_, ln2_b + l * H_, xb);
    }

    qa_kernel<<<M_, blk, 0, stream>>>(x, qa_w, qa_b, emis);
    crf_kernel<<<1, 64, 0, stream>>>(emis, attn_mask, start_pos, end_pos,
                                     crf_start, crf_end, crf_trans, out);
}

// Round 4
// 1398.054 us; speedup vs baseline: 10.1554x; 1.4413x over previous
//
#include <hip/hip_runtime.h>
#include <hip/hip_bf16.h>
#include <math.h>

// Problem constants
#define B_  4
#define S_  512
#define H_  768
#define NH_ 12
#define DH_ 64
#define FF_ 3072
#define L_  6
#define V_  30522
#define QKVN 2304          // fused QKV output width
#define M_  (B_ * S_)      // 2048 tokens

typedef short s16x8 __attribute__((ext_vector_type(8)));
typedef short s16x4v __attribute__((ext_vector_type(4)));
typedef float f32x4 __attribute__((ext_vector_type(4)));

__device__ __forceinline__ void gload_lds16(const void* g, void* l) {
    __builtin_amdgcn_global_load_lds(
        (const __attribute__((address_space(1))) void*)g,
        (__attribute__((address_space(3))) void*)l,
        16, 0, 0);
}

__device__ __forceinline__ ushort f2bu(float x) {
    __hip_bfloat16 h = __float2bfloat16(x);
    return *(ushort*)&h;
}

// read 8 contiguous bf16 from LDS as two 8B chunks (8B-aligned offsets only)
__device__ __forceinline__ s16x8 lds_frag(const ushort* p) {
    s16x4v lo = *(const s16x4v*)p;
    s16x4v hi = *(const s16x4v*)(p + 4);
    return __builtin_shufflevector(lo, hi, 0, 1, 2, 3, 4, 5, 6, 7);
}

// ---------------------------------------------------------------------------
// Embedding gather + LayerNorm -> x (fp32) and xb (bf16 shadow).
// ---------------------------------------------------------------------------
__global__ __launch_bounds__(256) void embed_ln_kernel(
    const int* __restrict__ ids, const int* __restrict__ tt,
    const float* __restrict__ wemb, const float* __restrict__ pemb,
    const float* __restrict__ temb, const float* __restrict__ g,
    const float* __restrict__ bb, float* __restrict__ x,
    __hip_bfloat16* __restrict__ xb)
{
    const int t = blockIdx.x;
    const int s = t % S_;
    const int tid = threadIdx.x;
    __shared__ float red[256];

    const float* wr = wemb + (size_t)ids[t] * H_;
    const float* pr = pemb + (size_t)s * H_;
    const float* tr = temb + (size_t)tt[t] * H_;

    float v[3];
    float sum = 0.f;
#pragma unroll
    for (int i = 0; i < 3; i++) {
        int c = tid + i * 256;
        v[i] = wr[c] + pr[c] + tr[c];
        sum += v[i];
    }
    red[tid] = sum; __syncthreads();
    for (int st = 128; st > 0; st >>= 1) { if (tid < st) red[tid] += red[tid + st]; __syncthreads(); }
    const float mean = red[0] / (float)H_;
    __syncthreads();
    float s2 = 0.f;
#pragma unroll
    for (int i = 0; i < 3; i++) { float d = v[i] - mean; s2 += d * d; }
    red[tid] = s2; __syncthreads();
    for (int st = 128; st > 0; st >>= 1) { if (tid < st) red[tid] += red[tid + st]; __syncthreads(); }
    const float rstd = rsqrtf(red[0] / (float)H_ + 1e-12f);
#pragma unroll
    for (int i = 0; i < 3; i++) {
        int c = tid + i * 256;
        float o = (v[i] - mean) * rstd * g[c] + bb[c];
        x[(size_t)t * H_ + c] = o;
        xb[(size_t)t * H_ + c] = __float2bfloat16(o);
    }
}

// ---------------------------------------------------------------------------
// Per-layer weight prep, ONE launch: transposes wq|wk|wv -> Wt_qkv, wo -> Wt_o,
// w1 -> Wt_1, w2 -> Wt_2 (all fp32 [K][N] -> bf16 [N][K]) + bias concat.
// Grid linearized over 32x32 tiles; block (32,8).
// ---------------------------------------------------------------------------
__device__ __forceinline__ void tr_tile(
    const float* __restrict__ src, ushort* __restrict__ dst,
    int K, int N, int t, int ncols, float (*tile)[33])
{
    const int tx = threadIdx.x, ty = threadIdx.y;
    const int n0 = (t % ncols) * 32;
    const int k0 = (t / ncols) * 32;
#pragma unroll
    for (int i = 0; i < 4; i++)
        tile[ty + 8 * i][tx] = src[(size_t)(k0 + ty + 8 * i) * N + n0 + tx];
    __syncthreads();
#pragma unroll
    for (int i = 0; i < 4; i++)
        dst[(size_t)(n0 + ty + 8 * i) * K + k0 + tx] = f2bu(tile[tx][ty + 8 * i]);
}

__global__ __launch_bounds__(256) void prep_layer_kernel(
    const float* __restrict__ wq, const float* __restrict__ wk,
    const float* __restrict__ wv, const float* __restrict__ wo,
    const float* __restrict__ w1, const float* __restrict__ w2,
    const float* __restrict__ bq, const float* __restrict__ bk,
    const float* __restrict__ bv,
    ushort* __restrict__ Wt_qkv, ushort* __restrict__ Wt_o,
    ushort* __restrict__ Wt_1, ushort* __restrict__ Wt_2,
    float* __restrict__ b_qkv)
{
    __shared__ float tile[32][33];
    const int id = blockIdx.x;
    if (id < 1728) {                      // QKV: 3 x 576 tiles of 768x768
        const int mat = id / 576, t = id % 576;
        const float* src = (mat == 0) ? wq : (mat == 1) ? wk : wv;
        tr_tile(src, Wt_qkv + (size_t)mat * H_ * H_, H_, H_, t, 24, tile);
    } else if (id < 2304) {               // O: 576 tiles
        tr_tile(wo, Wt_o, H_, H_, id - 1728, 24, tile);
    } else if (id < 4608) {               // W1: 768x3072, 2304 tiles
        tr_tile(w1, Wt_1, H_, FF_, id - 2304, 96, tile);
    } else if (id < 6912) {               // W2: 3072x768, 2304 tiles
        tr_tile(w2, Wt_2, FF_, H_, id - 4608, 24, tile);
    } else {                              // bias concat (9 blocks x 256)
        int i = (id - 6912) * 256 + threadIdx.y * 32 + threadIdx.x;
        if (i < QKVN)
            b_qkv[i] = (i < H_) ? bq[i] : ((i < 2 * H_) ? bk[i - H_] : bv[i - 2 * H_]);
    }
}

// ---------------------------------------------------------------------------
// bf16 MFMA GEMM (m97 structure): C[M][N] = A[M][K] @ Bt[N][K]^T + bias.
// 128x128 tile, BK=32, 256 thr = 4 waves (2x2 of 64x64), 16x16x32 MFMA.
// EPI: 0=none 1=exact gelu.  OUTBF: bf16 out.
// ---------------------------------------------------------------------------
#define TM 128
#define TN 128
#define TK 32

template<int EPI, int OUTBF>
__global__ __launch_bounds__(256) void gemm_mfma_kernel(
    const ushort* __restrict__ A, const ushort* __restrict__ Bt,
    const float* __restrict__ bias, void* __restrict__ Cout,
    int M, int K, int N)
{
    __shared__ ushort As[TM * TK];   // [m][k]
    __shared__ ushort Bs[TN * TK];   // [n][k]
    const int tid  = threadIdx.x;
    const int lane = tid & 63;
    const int wave = tid >> 6;
    const int m0 = blockIdx.y * TM;
    const int n0 = blockIdx.x * TN;
    const int wm = (wave >> 1) * 64;
    const int wn = (wave & 1) * 64;

    f32x4 acc[4][4];
#pragma unroll
    for (int i = 0; i < 4; i++)
#pragma unroll
        for (int j = 0; j < 4; j++)
            acc[i][j] = (f32x4){0.f, 0.f, 0.f, 0.f};

    const int c0 = wave * 2;
    const int rr = lane >> 2;
    const int ko = (lane & 3) * 8;
    const ushort* aS0 = A  + (size_t)(m0 + c0 * 16 + rr)       * K + ko;
    const ushort* aS1 = A  + (size_t)(m0 + (c0 + 1) * 16 + rr) * K + ko;
    const ushort* bS0 = Bt + (size_t)(n0 + c0 * 16 + rr)       * K + ko;
    const ushort* bS1 = Bt + (size_t)(n0 + (c0 + 1) * 16 + rr) * K + ko;
    ushort* aD0 = &As[(c0 * 16) * TK];
    ushort* aD1 = &As[((c0 + 1) * 16) * TK];
    ushort* bD0 = &Bs[(c0 * 16) * TK];
    ushort* bD1 = &Bs[((c0 + 1) * 16) * TK];

    const int fr = lane & 15;
    const int fk = (lane >> 4) * 8;

    for (int k0 = 0; k0 < K; k0 += TK) {
        __syncthreads();
        gload_lds16(aS0 + k0, aD0);
        gload_lds16(aS1 + k0, aD1);
        gload_lds16(bS0 + k0, bD0);
        gload_lds16(bS1 + k0, bD1);
        __syncthreads();

        s16x8 af[4], bf[4];
#pragma unroll
        for (int i = 0; i < 4; i++)
            af[i] = *(const s16x8*)&As[(wm + i * 16 + fr) * TK + fk];
#pragma unroll
        for (int j = 0; j < 4; j++)
            bf[j] = *(const s16x8*)&Bs[(wn + j * 16 + fr) * TK + fk];
#pragma unroll
        for (int i = 0; i < 4; i++)
#pragma unroll
            for (int j = 0; j < 4; j++)
                acc[i][j] = __builtin_amdgcn_mfma_f32_16x16x32_bf16(
                    af[i], bf[j], acc[i][j], 0, 0, 0);
    }

    const int ecol = lane & 15;
    const int erow = (lane >> 4) * 4;
#pragma unroll
    for (int j = 0; j < 4; j++) {
        const int gcol = n0 + wn + j * 16 + ecol;
        const float bv = bias[gcol];
#pragma unroll
        for (int i = 0; i < 4; i++) {
#pragma unroll
            for (int r = 0; r < 4; r++) {
                const int grow = m0 + wm + i * 16 + erow + r;
                float v = acc[i][j][r] + bv;
                if (EPI == 1) v = v * 0.5f * (1.0f + erff(v * 0.70710678118654752f));
                if (OUTBF)
                    ((ushort*)Cout)[(size_t)grow * N + gcol] = f2bu(v);
                else
                    ((float*)Cout)[(size_t)grow * N + gcol] = v;
            }
        }
    }
}

// ---------------------------------------------------------------------------
// MFMA flash attention.  QKV is bf16 [token][2304] (q|k|v, head-major DH=64).
// Block = (64 q-tile, head, batch), 256 thr = 4 waves; wave owns 16 q-rows.
// Per 64-key tile: S = QK^T (MFMA) -> online softmax (C-layout, 16-lane
// shuffles) -> P via LDS -> O += P V (MFMA, V transposed in LDS).
// LDS row stride 68 shorts: b64 accesses 8B-aligned, conflicts <=4-way.
// ---------------------------------------------------------------------------
#define VST 68

__global__ __launch_bounds__(256) void flash_attn_mfma_kernel(
    const ushort* __restrict__ QKV, const int* __restrict__ amask,
    __hip_bfloat16* __restrict__ Octx)
{
    const int q0 = blockIdx.x * 64, h = blockIdx.y, b = blockIdx.z;
    const int tid = threadIdx.x, lane = tid & 63, wave = tid >> 6;
    __shared__ ushort Qs[64 * VST];       // [q][d]
    __shared__ ushort Ks[64 * VST];       // [key][d]
    __shared__ ushort Vt[64 * VST];       // [d][key]
    __shared__ ushort Ps[4][16 * VST];    // per-wave [q][key]
    __shared__ float biasS[S_];

    for (int i = tid; i < S_; i += 256)
        biasS[i] = amask[b * S_ + i] ? 0.f : -1e9f;

    {   // stage Q: thread -> q = tid>>2, d-group (tid&3)*16
        const ushort* qb = QKV + (size_t)(b * S_ + q0) * QKVN + h * DH_;
        const int q = tid >> 2, dg = (tid & 3) * 16;
        s16x8 v0 = *(const s16x8*)(qb + (size_t)q * QKVN + dg);
        s16x8 v1 = *(const s16x8*)(qb + (size_t)q * QKVN + dg + 8);
        ushort* d = &Qs[q * VST + dg];
        *(s16x4v*)(d)      = __builtin_shufflevector(v0, v0, 0, 1, 2, 3);
        *(s16x4v*)(d + 4)  = __builtin_shufflevector(v0, v0, 4, 5, 6, 7);
        *(s16x4v*)(d + 8)  = __builtin_shufflevector(v1, v1, 0, 1, 2, 3);
        *(s16x4v*)(d + 12) = __builtin_shufflevector(v1, v1, 4, 5, 6, 7);
    }
    __syncthreads();

    const int fm = lane & 15;
    const int fk = (lane >> 4) * 8;

    // Q fragments are invariant across key tiles
    const s16x8 aq0 = lds_frag(&Qs[(wave * 16 + fm) * VST + fk]);
    const s16x8 aq1 = lds_frag(&Qs[(wave * 16 + fm) * VST + 32 + fk]);

    f32x4 acc[4];
#pragma unroll
    for (int j = 0; j < 4; j++) acc[j] = (f32x4){0.f, 0.f, 0.f, 0.f};
    float m_i[4], l_i[4];
#pragma unroll
    for (int r = 0; r < 4; r++) { m_i[r] = -INFINITY; l_i[r] = 0.f; }

    for (int kt = 0; kt < S_; kt += 64) {
        __syncthreads();   // protect Ks/Vt from prior-tile readers
        {   // stage K tile [key][d]
            const ushort* kb = QKV + (size_t)(b * S_ + kt) * QKVN + H_ + h * DH_;
            const int ky = tid >> 2, dg = (tid & 3) * 16;
            s16x8 v0 = *(const s16x8*)(kb + (size_t)ky * QKVN + dg);
            s16x8 v1 = *(const s16x8*)(kb + (size_t)ky * QKVN + dg + 8);
            ushort* d = &Ks[ky * VST + dg];
            *(s16x4v*)(d)      = __builtin_shufflevector(v0, v0, 0, 1, 2, 3);
            *(s16x4v*)(d + 4)  = __builtin_shufflevector(v0, v0, 4, 5, 6, 7);
            *(s16x4v*)(d + 8)  = __builtin_shufflevector(v1, v1, 0, 1, 2, 3);
            *(s16x4v*)(d + 12) = __builtin_shufflevector(v1, v1, 4, 5, 6, 7);
        }
        {   // stage V transposed [d][key]; coalesced reads (lanes over d)
            const ushort* vb = QKV + (size_t)(b * S_ + kt) * QKVN + 2 * H_ + h * DH_;
            const int d = tid & 63, kg = tid >> 6;
#pragma unroll
            for (int kp = 0; kp < 8; kp++) {
                const int key = kg * 16 + kp * 2;
                ushort u0 = vb[(size_t)key * QKVN + d];
                ushort u1 = vb[(size_t)(key + 1) * QKVN + d];
                ushort2 u; u.x = u0; u.y = u1;
                *(ushort2*)&Vt[d * VST + key] = u;
            }
        }
        __syncthreads();

        // S = Q K^T  (C-layout: col=key=lane&15 within ctile, row=q=(lane>>4)*4+r)
        f32x4 sc[4];
#pragma unroll
        for (int jj = 0; jj < 4; jj++) {
            s16x8 b0 = lds_frag(&Ks[(jj * 16 + fm) * VST + fk]);
            s16x8 b1 = lds_frag(&Ks[(jj * 16 + fm) * VST + 32 + fk]);
            f32x4 z = (f32x4){0.f, 0.f, 0.f, 0.f};
            z = __builtin_amdgcn_mfma_f32_16x16x32_bf16(aq0, b0, z, 0, 0, 0);
            z = __builtin_amdgcn_mfma_f32_16x16x32_bf16(aq1, b1, z, 0, 0, 0);
            sc[jj] = z;
        }

        // online softmax, per local q-row r
#pragma unroll
        for (int r = 0; r < 4; r++) {
            float mx = -INFINITY;
#pragma unroll
            for (int jj = 0; jj < 4; jj++) {
                float v = sc[jj][r] * 0.125f + biasS[kt + jj * 16 + fm];
                sc[jj][r] = v;
                mx = fmaxf(mx, v);
            }
#pragma unroll
            for (int msk = 1; msk < 16; msk <<= 1) mx = fmaxf(mx, __shfl_xor(mx, msk));
            const float newm = fmaxf(m_i[r], mx);
            const float alpha = __expf(m_i[r] - newm);
            m_i[r] = newm;
            float rs = 0.f;
#pragma unroll
            for (int jj = 0; jj < 4; jj++) {
                float p = __expf(sc[jj][r] - newm);
                sc[jj][r] = p; rs += p;
            }
#pragma unroll
            for (int msk = 1; msk < 16; msk <<= 1) rs += __shfl_xor(rs, msk);
            l_i[r] = l_i[r] * alpha + rs;
#pragma unroll
            for (int jj = 0; jj < 4; jj++) acc[jj][r] *= alpha;
        }

        // P -> per-wave LDS (bf16), then read back as A-fragments
#pragma unroll
        for (int jj = 0; jj < 4; jj++)
#pragma unroll
            for (int r = 0; r < 4; r++)
                Ps[wave][((lane >> 4) * 4 + r) * VST + jj * 16 + fm] = f2bu(sc[jj][r]);

        const s16x8 ap0 = lds_frag(&Ps[wave][fm * VST + fk]);
        const s16x8 ap1 = lds_frag(&Ps[wave][fm * VST + 32 + fk]);

        // O += P V
#pragma unroll
        for (int jj = 0; jj < 4; jj++) {
            s16x8 b0 = lds_frag(&Vt[(jj * 16 + fm) * VST + fk]);
            s16x8 b1 = lds_frag(&Vt[(jj * 16 + fm) * VST + 32 + fk]);
            acc[jj] = __builtin_amdgcn_mfma_f32_16x16x32_bf16(ap0, b0, acc[jj], 0, 0, 0);
            acc[jj] = __builtin_amdgcn_mfma_f32_16x16x32_bf16(ap1, b1, acc[jj], 0, 0, 0);
        }
    }

    // epilogue: O[q][d] / l
#pragma unroll
    for (int r = 0; r < 4; r++) {
        const int q = q0 + wave * 16 + (lane >> 4) * 4 + r;
        const float inv = 1.0f / l_i[r];
        __hip_bfloat16* op = Octx + (size_t)(b * S_ + q) * H_ + h * DH_;
#pragma unroll
        for (int jj = 0; jj < 4; jj++)
            op[jj * 16 + fm] = __float2bfloat16(acc[jj][r] * inv);
    }
}

// ---------------------------------------------------------------------------
// x = LN(x + delta) in place; also writes bf16 shadow xb.
// ---------------------------------------------------------------------------
__global__ __launch_bounds__(256) void add_ln_kernel(
    float* __restrict__ x, const float* __restrict__ delta,
    const float* __restrict__ g, const float* __restrict__ bb,
    __hip_bfloat16* __restrict__ xb)
{
    const int t = blockIdx.x;
    const int tid = threadIdx.x;
    __shared__ float red[256];
    const size_t base = (size_t)t * H_;

    float v[3];
    float sum = 0.f;
#pragma unroll
    for (int i = 0; i < 3; i++) {
        int c = tid + i * 256;
        v[i] = x[base + c] + delta[base + c];
        sum += v[i];
    }
    red[tid] = sum; __syncthreads();
    for (int st = 128; st > 0; st >>= 1) { if (tid < st) red[tid] += red[tid + st]; __syncthreads(); }
    const float mean = red[0] / (float)H_;
    __syncthreads();
    float s2 = 0.f;
#pragma unroll
    for (int i = 0; i < 3; i++) { float d = v[i] - mean; s2 += d * d; }
    red[tid] = s2; __syncthreads();
    for (int st = 128; st > 0; st >>= 1) { if (tid < st) red[tid] += red[tid + st]; __syncthreads(); }
    const float rstd = rsqrtf(red[0] / (float)H_ + 1e-12f);
#pragma unroll
    for (int i = 0; i < 3; i++) {
        int c = tid + i * 256;
        float o = (v[i] - mean) * rstd * g[c] + bb[c];
        x[base + c] = o;
        xb[base + c] = __float2bfloat16(o);
    }
}

// ---------------------------------------------------------------------------
// QA head: emissions[t,0..1] = x[t,:] @ qa_w + qa_b.
// ---------------------------------------------------------------------------
__global__ __launch_bounds__(256) void qa_kernel(
    const float* __restrict__ x, const float* __restrict__ qa_w,
    const float* __restrict__ qa_b, float* __restrict__ em)
{
    const int t = blockIdx.x;
    const int tid = threadIdx.x;
    __shared__ float r0[256], r1[256];
    float s0 = 0.f, s1 = 0.f;
#pragma unroll
    for (int i = 0; i < 3; i++) {
        int c = tid + i * 256;
        float xv = x[(size_t)t * H_ + c];
        s0 += xv * qa_w[c * 2 + 0];
        s1 += xv * qa_w[c * 2 + 1];
    }
    r0[tid] = s0; r1[tid] = s1; __syncthreads();
    for (int st = 128; st > 0; st >>= 1) {
        if (tid < st) { r0[tid] += r0[tid + st]; r1[tid] += r1[tid + st]; }
        __syncthreads();
    }
    if (tid == 0) {
        em[(size_t)t * 2 + 0] = r0[0] + qa_b[0];
        em[(size_t)t * 2 + 1] = r1[0] + qa_b[1];
    }
}

// ---------------------------------------------------------------------------
// CRF via log-semiring parallel reduction.  One block, 256 thr:
// 64 threads per sequence; each combines 8 of the 512 transition matrices
// serially, then an ordered LDS tree (depth 6).  The numerator is a
// parallel sum.  Masked steps / padding = log-identity (NEG off-diag).
// ---------------------------------------------------------------------------
__device__ __forceinline__ float lse2(float a, float b) {
    float m = fmaxf(a, b);
    return m + log1pf(expf(-fabsf(a - b)));
}

__device__ __forceinline__ float4 lsem_comb(float4 a, float4 b) {
    // layout: x=m00 y=m01 z=m10 w=m11 ;  out[i][j] = lse_k(a[i][k]+b[k][j])
    float4 r;
    r.x = lse2(a.x + b.x, a.y + b.z);
    r.y = lse2(a.x + b.y, a.y + b.w);
    r.z = lse2(a.z + b.x, a.w + b.z);
    r.w = lse2(a.z + b.y, a.w + b.w);
    return r;
}

__global__ __launch_bounds__(256) void crf_parallel_kernel(
    const float* __restrict__ em, const int* __restrict__ amask,
    const int* __restrict__ spos, const int* __restrict__ epos,
    const float* __restrict__ startT, const float* __restrict__ endT,
    const float* __restrict__ trans, float* __restrict__ out)
{
    __shared__ float4 mats[B_][64];
    __shared__ float numred[B_][64];
    __shared__ float cntred[B_][64];
    __shared__ float llh[B_];
    const int tid = threadIdx.x;
    const int s = tid >> 6;          // sequence
    const int j = tid & 63;          // local index
    const float NEG = -1e30f;

    const int sp = spos[s], ep = epos[s];
    const bool valid = (sp >= 0) && (sp < S_) && (ep >= 0) && (ep < S_) && (sp <= ep);
    const float* e = em + (size_t)s * S_ * 2;
    const int* mk = amask + s * S_;
    const float t00 = trans[0], t01 = trans[1], t10 = trans[2], t11 = trans[3];

    float4 C = make_float4(0.f, NEG, NEG, 0.f);   // identity
    float num = 0.f, cnt = 0.f;
#pragma unroll
    for (int k = 0; k < 8; k++) {
        const int t = j * 8 + 1 + k;             // 1..512 (512 = pad)
        float4 Mt = make_float4(0.f, NEG, NEG, 0.f);
        if (t < S_ && mk[t]) {
            const float e0 = e[2 * t], e1 = e[2 * t + 1];
            Mt = make_float4(t00 + e0, t01 + e1, t10 + e0, t11 + e1);
            const int tp = (valid && (t - 1) >= sp && (t - 1) <= ep) ? 1 : 0;
            const int tc = (valid && t >= sp && t <= ep) ? 1 : 0;
            const float tr = tp ? (tc ? t11 : t10) : (tc ? t01 : t00);
            num += tr + (tc ? e1 : e0);
            cnt += 1.f;
        }
        C = (k == 0) ? Mt : lsem_comb(C, Mt);
    }
    if (j == 0) {
        const int tag0 = (valid && 0 >= sp && 0 <= ep) ? 1 : 0;
        num += startT[tag0] + e[tag0];
        cnt += mk[0] ? 1.f : 0.f;
    }
    mats[s][j] = C;
    numred[s][j] = num;
    cntred[s][j] = cnt;
    __syncthreads();

    // ordered matrix tree: 64 -> 1
    for (int st = 32; st >= 1; st >>= 1) {
        float4 a, b;
        const bool act = (j < st);
        if (act) { a = mats[s][2 * j]; b = mats[s][2 * j + 1]; }
        __syncthreads();
        if (act) mats[s][j] = lsem_comb(a, b);
        __syncthreads();
    }
    // scalar sums
    for (int st = 32; st >= 1; st >>= 1) {
        if (j < st) {
            numred[s][j] += numred[s][j + st];
            cntred[s][j] += cntred[s][j + st];
        }
        __syncthreads();
    }

    if (j == 0) {
        float numT = numred[s][0];
        const int last_idx = (int)(cntred[s][0] + 0.5f) - 1;
        const int ltag = (valid && last_idx >= sp && last_idx <= ep) ? 1 : 0;
        numT += endT[ltag];
        const float a00 = startT[0] + e[0];
        const float a01 = startT[1] + e[1];
        const float4 P = mats[s][0];
        const float aF0 = lse2(a00 + P.x, a01 + P.z);
        const float aF1 = lse2(a00 + P.y, a01 + P.w);
        const float logZ = lse2(aF0 + endT[0], aF1 + endT[1]);
        llh[s] = numT - logZ;
    }
    __syncthreads();
    if (tid == 0)
        out[0] = -(llh[0] + llh[1] + llh[2] + llh[3]);
}

// ---------------------------------------------------------------------------
// Launch
// ---------------------------------------------------------------------------
extern "C" void kernel_launch(void* const* d_in, const int* in_sizes, int n_in,
                              void* d_out, int out_size, void* d_ws, size_t ws_size,
                              hipStream_t stream)
{
    const int*   input_ids  = (const int*)  d_in[0];
    const int*   attn_mask  = (const int*)  d_in[1];
    const int*   token_type = (const int*)  d_in[2];
    const int*   start_pos  = (const int*)  d_in[3];
    const int*   end_pos    = (const int*)  d_in[4];
    const float* word_emb   = (const float*)d_in[5];
    const float* pos_emb    = (const float*)d_in[6];
    const float* type_emb   = (const float*)d_in[7];
    const float* emb_ln_g   = (const float*)d_in[8];
    const float* emb_ln_b   = (const float*)d_in[9];
    const float* Wq         = (const float*)d_in[10];
    const float* bq         = (const float*)d_in[11];
    const float* Wk         = (const float*)d_in[12];
    const float* bk         = (const float*)d_in[13];
    const float* Wv         = (const float*)d_in[14];
    const float* bv         = (const float*)d_in[15];
    const float* Wo         = (const float*)d_in[16];
    const float* bo         = (const float*)d_in[17];
    const float* ln1_g      = (const float*)d_in[18];
    const float* ln1_b      = (const float*)d_in[19];
    const float* W1         = (const float*)d_in[20];
    const float* b1         = (const float*)d_in[21];
    const float* W2         = (const float*)d_in[22];
    const float* b2         = (const float*)d_in[23];
    const float* ln2_g      = (const float*)d_in[24];
    const float* ln2_b      = (const float*)d_in[25];
    const float* qa_w       = (const float*)d_in[26];
    const float* qa_b       = (const float*)d_in[27];
    const float* crf_start  = (const float*)d_in[28];
    const float* crf_end    = (const float*)d_in[29];
    const float* crf_trans  = (const float*)d_in[30];
    float* out = (float*)d_out;

    // Workspace carve-up (fp32 region first, then bf16 region)
    float*  x      = (float*)d_ws;                                  // M*H
    float*  tmp768 = x + (size_t)M_ * H_;                           // M*H
    float*  emis   = tmp768 + (size_t)M_ * H_;                      // M*2
    float*  b_qkv  = emis + (size_t)M_ * 2;                         // 2304
    ushort* xb     = (ushort*)(b_qkv + QKVN);                       // M*H
    ushort* qkvb   = xb + (size_t)M_ * H_;                          // M*2304
    ushort* ctxb   = qkvb + (size_t)M_ * QKVN;                      // M*H
    ushort* hb     = ctxb + (size_t)M_ * H_;                        // M*FF
    ushort* Wt_qkv = hb + (size_t)M_ * FF_;                         // 2304*768
    ushort* Wt_o   = Wt_qkv + (size_t)QKVN * H_;                    // 768*768
    ushort* Wt_1   = Wt_o + (size_t)H_ * H_;                        // 3072*768
    ushort* Wt_2   = Wt_1 + (size_t)FF_ * H_;                       // 768*3072

    dim3 blk(256);
    dim3 tblk(32, 8);

    embed_ln_kernel<<<M_, blk, 0, stream>>>(input_ids, token_type, word_emb, pos_emb,
                                            type_emb, emb_ln_g, emb_ln_b, x,
                                            (__hip_bfloat16*)xb);

    const dim3 gQKV(QKVN / TN, M_ / TM);   // 18 x 16
    const dim3 gO(H_ / TN, M_ / TM);       // 6 x 16
    const dim3 gF1(FF_ / TN, M_ / TM);     // 24 x 16
    const dim3 gA(S_ / 64, NH_, B_);       // 8 x 12 x 4

    for (int l = 0; l < L_; l++) {
        prep_layer_kernel<<<6921, tblk, 0, stream>>>(
            Wq + (size_t)l * H_ * H_, Wk + (size_t)l * H_ * H_,
            Wv + (size_t)l * H_ * H_, Wo + (size_t)l * H_ * H_,
            W1 + (size_t)l * H_ * FF_, W2 + (size_t)l * FF_ * H_,
            bq + l * H_, bk + l * H_, bv + l * H_,
            Wt_qkv, Wt_o, Wt_1, Wt_2, b_qkv);

        gemm_mfma_kernel<0, 1><<<gQKV, blk, 0, stream>>>(
            xb, Wt_qkv, b_qkv, qkvb, M_, H_, QKVN);

        flash_attn_mfma_kernel<<<gA, blk, 0, stream>>>(
            qkvb, attn_mask, (__hip_bfloat16*)ctxb);

        gemm_mfma_kernel<0, 0><<<gO, blk, 0, stream>>>(
            ctxb, Wt_o, bo + l * H_, tmp768, M_, H_, H_);
        add_ln_kernel<<<M_, blk, 0, stream>>>(x, tmp768, ln1_g + l * H_, ln1_b + l * H_,
                                              (__hip_bfloat16*)xb);

        gemm_mfma_kernel<1, 1><<<gF1, blk, 0, stream>>>(
            xb, Wt_1, b1 + l * FF_, hb, M_, H_, FF_);
        gemm_mfma_kernel<0, 0><<<gO, blk, 0, stream>>>(
            hb, Wt_2, b2 + l * H_, tmp768, M_, FF_, H_);
        add_ln_kernel<<<M_, blk, 0, stream>>>(x, tmp768, ln2_g + l * H_, ln2_b + l * H_,
                                              (__hip_bfloat16*)xb);
    }

    qa_kernel<<<M_, blk, 0, stream>>>(x, qa_w, qa_b, emis);
    crf_parallel_kernel<<<1, 256, 0, stream>>>(emis, attn_mask, start_pos, end_pos,
                                               crf_start, crf_end, crf_trans, out);
}